// Round 8
// baseline (235.199 us; speedup 1.0000x reference)
//
#include <hip/hip_runtime.h>
#include <cstddef>

#define N_PIX 4096
#define HW 64
#define LOG2E 1.4426950408889634f
#define SHIFT2 28.8539008177793f   // 20 * log2(e)

typedef __attribute__((ext_vector_type(8))) short bf16x8;
typedef __attribute__((ext_vector_type(4))) float f32x4;

static __device__ __forceinline__ unsigned short f2bf(float f) {
    union { float f; unsigned u; } v; v.f = f;
    unsigned r = v.u + 0x7fffu + ((v.u >> 16) & 1u);   // RNE
    return (unsigned short)(r >> 16);
}
static __device__ __forceinline__ float bf2f(unsigned short s) {
    union { unsigned u; float f; } v; v.u = (unsigned)s << 16;
    return v.f;
}
// (bf16(hi)<<16)|bf16(lo), truncating: one v_perm_b32
static __device__ __forceinline__ unsigned pack_bf16_trunc(float lo, float hi) {
    union { float f; unsigned u; } a, b; a.f = hi; b.f = lo;
    return __builtin_amdgcn_perm(a.u, b.u, 0x07060302u);
}

// ---------------------------------------------------------------------------
// x [b][256 ci][4096 px] fp32  ->  xbf [b][4096 px][256 ci] bf16
// ---------------------------------------------------------------------------
__global__ __launch_bounds__(256) void x_transpose(
    const float* __restrict__ x, unsigned short* __restrict__ xbf)
{
    __shared__ unsigned short Ts[64][72];
    const int tid = threadIdx.x;
    const int px0 = blockIdx.x * 64, ci0 = blockIdx.y * 64, b = blockIdx.z;
    const float* xb = x + ((size_t)b * 256 + ci0) * N_PIX;

#pragma unroll
    for (int r = 0; r < 4; ++r) {
        int c = r * 16 + (tid >> 4);
        int p4 = (tid & 15) * 4;
        float4 v = *(const float4*)&xb[(size_t)c * N_PIX + px0 + p4];
        Ts[c][p4 + 0] = f2bf(v.x);
        Ts[c][p4 + 1] = f2bf(v.y);
        Ts[c][p4 + 2] = f2bf(v.z);
        Ts[c][p4 + 3] = f2bf(v.w);
    }
    __syncthreads();
#pragma unroll
    for (int r = 0; r < 2; ++r) {
        int id = tid * 2 + r;
        int p = id >> 3, c8 = (id & 7) * 8;
        ushort4 lo, hi;
        lo.x = Ts[c8 + 0][p]; lo.y = Ts[c8 + 1][p];
        lo.z = Ts[c8 + 2][p]; lo.w = Ts[c8 + 3][p];
        hi.x = Ts[c8 + 4][p]; hi.y = Ts[c8 + 5][p];
        hi.z = Ts[c8 + 6][p]; hi.w = Ts[c8 + 7][p];
        size_t off = ((size_t)b * N_PIX + px0 + p) * 256 + ci0 + c8;
        *(ushort4*)&xbf[off]     = lo;
        *(ushort4*)&xbf[off + 4] = hi;
    }
}

// ---------------------------------------------------------------------------
// Weights -> wAll [kb 0..71][320 rows][32 kin] bf16 (A-frag order).
// Rows: 0..255 wv, 256..287 wq (scaled by log2e), 288..319 wk.
// ---------------------------------------------------------------------------
__global__ __launch_bounds__(256) void w_transform(
    const float* __restrict__ wq, const float* __restrict__ wk,
    const float* __restrict__ wv, unsigned short* __restrict__ wAll)
{
    int gid = blockIdx.x * 256 + threadIdx.x;
    if (gid >= 72 * 320 * 4) return;
    int part = gid & 3;
    int m = (gid >> 2) % 320;
    int kb = gid / 1280;
    int t = kb >> 3;
    int ci0 = (kb & 7) * 32 + part * 8;
    const float* src; int co; float sc = 1.f;
    if (m < 256)      { src = wv; co = m; }
    else if (m < 288) { src = wq; co = m - 256; sc = LOG2E; }
    else              { src = wk; co = m - 288; }
    ushort4 lo, hi;
    lo.x = f2bf(sc * src[((size_t)co * 256 + ci0 + 0) * 9 + t]);
    lo.y = f2bf(sc * src[((size_t)co * 256 + ci0 + 1) * 9 + t]);
    lo.z = f2bf(sc * src[((size_t)co * 256 + ci0 + 2) * 9 + t]);
    lo.w = f2bf(sc * src[((size_t)co * 256 + ci0 + 3) * 9 + t]);
    hi.x = f2bf(sc * src[((size_t)co * 256 + ci0 + 4) * 9 + t]);
    hi.y = f2bf(sc * src[((size_t)co * 256 + ci0 + 5) * 9 + t]);
    hi.z = f2bf(sc * src[((size_t)co * 256 + ci0 + 6) * 9 + t]);
    hi.w = f2bf(sc * src[((size_t)co * 256 + ci0 + 7) * 9 + t]);
    size_t off = ((size_t)kb * 320 + m) * 32 + part * 8;
    *(ushort4*)&wAll[off]     = lo;
    *(ushort4*)&wAll[off + 4] = hi;
}

// ---------------------------------------------------------------------------
// Unified conv implicit GEMM: 64co x 128px tiles, BK=64, ONE barrier/pair.
// A-fragments read DIRECTLY from global (wAll is L2-hot, coalesced 1KB/wave).
// B staged in ping-pong LDS with conflict-free lane->row mapping.
// blockIdx.y = ct: 0..3 -> V rows [64*ct); 4 -> QK rows 256..319.
// ---------------------------------------------------------------------------
__global__ __launch_bounds__(256) void conv_gemm_all(
    const unsigned short* __restrict__ xbf, const unsigned short* __restrict__ wAll,
    const float* __restrict__ bq, const float* __restrict__ bk,
    const float* __restrict__ bv,
    unsigned short* __restrict__ vbf, unsigned short* __restrict__ qt,
    unsigned short* __restrict__ kt)
{
    const int tid = threadIdx.x;
    const int w = tid >> 6, lane = tid & 63, quad = lane >> 4, l15 = lane & 15;
    const int px0 = blockIdx.x * 128;
    const int ct  = blockIdx.y;
    const int b   = blockIdx.z;
    const int row0 = ct * 64;                 // ct==4 -> rows 256..319 (QK)

    // Bl[buf][h][128 rows][40 shorts]  = 40 KB total
    __shared__ unsigned short Bl[2 * 2 * 128 * 40];

    const unsigned short* xb = xbf + (size_t)b * N_PIX * 256;

    // B staging: conflict-free mapping (lanes -> consecutive rows)
    const int brow  = tid & 127;              // row for both chunks
    const int bpart = tid >> 7;               // parts bpart, bpart+2
    const int py = (px0 + brow) >> 6, pxc = brow & 63;

    f32x4 acc[4][2];
#pragma unroll
    for (int cb = 0; cb < 4; ++cb)
#pragma unroll
        for (int jb = 0; jb < 2; ++jb) acc[cb][jb] = (f32x4){0.f, 0.f, 0.f, 0.f};

    auto load_b = [&](int kb0, bf16x8* bR) {
#pragma unroll
        for (int h = 0; h < 2; ++h) {
            int kb = kb0 + h;
            int t = kb >> 3, ci0 = (kb & 7) << 5;
            int dy = t / 3 - 1, dx = t - (t / 3) * 3 - 1;
            int gy = py + dy, gx = pxc + dx;
            bool valid = (unsigned)gy < 64u && (unsigned)gx < 64u;
            if (valid) {
                const unsigned short* s =
                    xb + ((size_t)(gy * 64 + gx) * 256 + ci0 + bpart * 8);
                bR[2 * h + 0] = *(const bf16x8*)&s[0];
                bR[2 * h + 1] = *(const bf16x8*)&s[16];   // part bpart+2
            } else {
                bR[2 * h + 0] = (bf16x8){0,0,0,0,0,0,0,0};
                bR[2 * h + 1] = (bf16x8){0,0,0,0,0,0,0,0};
            }
        }
    };
    auto store_b = [&](int buf, const bf16x8* bR) {
#pragma unroll
        for (int h = 0; h < 2; ++h) {
            *(bf16x8*)&Bl[buf * 10240 + h * 5120 + brow * 40 + bpart * 8]       = bR[2 * h + 0];
            *(bf16x8*)&Bl[buf * 10240 + h * 5120 + brow * 40 + (bpart + 2) * 8] = bR[2 * h + 1];
        }
    };

    bf16x8 bN[4];
    load_b(0, bN);
    store_b(0, bN);

    for (int kp = 0; kp < 36; ++kp) {
        __syncthreads();                       // Bl[kp&1] visible
        const bool hasN = (kp + 1 < 36);
        if (hasN) load_b(2 * (kp + 1), bN);    // global -> regs (next pair)

        // A frags JIT from global (L2-hot); B frags from LDS
#pragma unroll
        for (int h = 0; h < 2; ++h) {
            int kb = 2 * kp + h;
            bf16x8 af[4], bf[2];
#pragma unroll
            for (int cb = 0; cb < 4; ++cb)
                af[cb] = *(const bf16x8*)&wAll[((size_t)kb * 320 + row0 + cb * 16 + l15) * 32
                                               + quad * 8];
#pragma unroll
            for (int jb = 0; jb < 2; ++jb)
                bf[jb] = *(const bf16x8*)&Bl[(kp & 1) * 10240 + h * 5120
                                             + (w * 32 + jb * 16 + l15) * 40 + quad * 8];
#pragma unroll
            for (int cb = 0; cb < 4; ++cb)
#pragma unroll
                for (int jb = 0; jb < 2; ++jb)
                    acc[cb][jb] = __builtin_amdgcn_mfma_f32_16x16x32_bf16(
                        af[cb], bf[jb], acc[cb][jb], 0, 0, 0);
        }

        if (hasN) store_b((kp + 1) & 1, bN);   // write other buffer (safe)
    }

    if (ct < 4) {
#pragma unroll
        for (int cb = 0; cb < 4; ++cb) {
            int c = ct * 64 + cb * 16 + quad * 4;
#pragma unroll
            for (int r = 0; r < 4; ++r) {
                float bias = bv[c + r];
#pragma unroll
                for (int jb = 0; jb < 2; ++jb) {
                    int px = px0 + w * 32 + jb * 16 + l15;
                    vbf[((size_t)b * 256 + c + r) * N_PIX + px] = f2bf(acc[cb][jb][r] + bias);
                }
            }
        }
    } else {
#pragma unroll
        for (int cb = 0; cb < 4; ++cb) {
            int cl = cb * 16 + quad * 4;
#pragma unroll
            for (int r = 0; r < 4; ++r) {
                int c = cl + r;
                float bias = (c < 32) ? bq[c] * LOG2E : bk[c - 32];
#pragma unroll
                for (int jb = 0; jb < 2; ++jb) {
                    int px = px0 + w * 32 + jb * 16 + l15;
                    unsigned short val = f2bf(acc[cb][jb][r] + bias);
                    if (c < 32)
                        qt[((size_t)b * N_PIX + px) * 32 + c] = val;
                    else
                        kt[((size_t)b * N_PIX + px) * 32 + (c - 32)] = val;
                }
            }
        }
    }
}

// ---------------------------------------------------------------------------
// MFMA flash attention — j-tile 128, single barrier/iter, Pfrag ping-pong.
// qt pre-scaled by log2e; shift folded into MFMA C-init; P packed with
// v_perm_b32 (truncating bf16).
// ---------------------------------------------------------------------------
__global__ __launch_bounds__(256, 2) void fused_attn_mfma(
    const unsigned short* __restrict__ qt, const unsigned short* __restrict__ kt,
    const unsigned short* __restrict__ vbf,
    unsigned short* __restrict__ Abuf, float* __restrict__ lbuf, int iRange)
{
    const int tid  = threadIdx.x;
    const int w    = tid >> 6;
    const int lane = tid & 63;
    const int quad = lane >> 4;
    const int l15  = lane & 15;
    const int j0   = blockIdx.x * 128;
    const int b    = blockIdx.y;
    const int sp   = blockIdx.z;
    const int iBeg = sp * iRange;
    const int NI   = iRange / 64;

    const unsigned short* qtb = qt + (size_t)b * N_PIX * 32;
    const unsigned short* ktb = kt + (size_t)b * N_PIX * 32;
    const unsigned short* vb  = vbf + (size_t)b * 256 * N_PIX;

    __shared__ unsigned Pfrag[2][4096];   // 32 KB ping-pong (dwords)
    __shared__ float lred[4][128];

    bf16x8 kf[8];
#pragma unroll
    for (int jb = 0; jb < 8; ++jb)
        kf[jb] = *(const bf16x8*)&ktb[((size_t)(j0 + jb * 16 + l15)) * 32 + quad * 8];

    f32x4 acc[4][8];
#pragma unroll
    for (int cb = 0; cb < 4; ++cb)
#pragma unroll
        for (int jb = 0; jb < 8; ++jb)
            acc[cb][jb] = (f32x4){0.f, 0.f, 0.f, 0.f};

    float lpart[8] = {0.f, 0.f, 0.f, 0.f, 0.f, 0.f, 0.f, 0.f};

    const int wFrag = w >> 1;
    const int wL    = ((w & 1) << 5) + ((quad >> 1) << 4) + l15;
    const int wEl2  = (quad & 1) << 1;   // dword offset 0 or 2

    bf16x8 va[2][4];

    auto s_phase = [&](bf16x8 qa, int buf) {
#pragma unroll
        for (int jb = 0; jb < 8; ++jb) {
            f32x4 s = __builtin_amdgcn_mfma_f32_16x16x32_bf16(
                qa, kf[jb], (f32x4){-SHIFT2, -SHIFT2, -SHIFT2, -SHIFT2}, 0, 0, 0);
            float p0 = __builtin_amdgcn_exp2f(s[0]);
            float p1 = __builtin_amdgcn_exp2f(s[1]);
            float p2 = __builtin_amdgcn_exp2f(s[2]);
            float p3 = __builtin_amdgcn_exp2f(s[3]);
            lpart[jb] += (p0 + p1) + (p2 + p3);
            unsigned u0 = pack_bf16_trunc(p0, p1);
            unsigned u1 = pack_bf16_trunc(p2, p3);
            unsigned base = (((jb << 1) + wFrag) * 64 + wL) * 4 + wEl2;
            Pfrag[buf][base]     = u0;
            Pfrag[buf][base + 1] = u1;
        }
    };

    auto load_qa = [&](int i0) {
        return *(const bf16x8*)&qtb[((size_t)(i0 + w * 16 + l15)) * 32 + quad * 8];
    };
    auto load_va = [&](int i0) {
#pragma unroll
        for (int ks = 0; ks < 2; ++ks)
#pragma unroll
            for (int cb = 0; cb < 4; ++cb)
                va[ks][cb] = *(const bf16x8*)&vb[((size_t)(w * 64 + cb * 16 + l15)) * N_PIX
                                                 + i0 + ks * 32 + quad * 8];
    };

    // prologue
    load_va(iBeg);
    s_phase(load_qa(iBeg), 0);

    for (int n = 0; n < NI; ++n) {
        __syncthreads();               // P[n&1] ready for all waves
        const bool hasN = (n + 1 < NI);
        const int inext = iBeg + (n + 1) * 64;
        bf16x8 qaN;
        if (hasN) qaN = load_qa(inext);

        // ---- O(n): reads Pfrag[n&1] + va (loaded for iter n)
#pragma unroll
        for (int ks = 0; ks < 2; ++ks) {
            bf16x8 pb[8];
#pragma unroll
            for (int jb = 0; jb < 8; ++jb)
                pb[jb] = *(const bf16x8*)&Pfrag[n & 1][(((jb << 1) + ks) * 64 + lane) * 4];
#pragma unroll
            for (int cb = 0; cb < 4; ++cb)
#pragma unroll
                for (int jb = 0; jb < 8; ++jb)
                    acc[cb][jb] = __builtin_amdgcn_mfma_f32_16x16x32_bf16(
                        va[ks][cb], pb[jb], acc[cb][jb], 0, 0, 0);
        }

        // ---- prefetch va(n+1) then S(n+1) into other buffer
        if (hasN) {
            load_va(inext);
            s_phase(qaN, (n + 1) & 1);
        }
    }

    // ---- l reduction
#pragma unroll
    for (int jb = 0; jb < 8; ++jb) {
        float v = lpart[jb];
        v += __shfl_xor(v, 16, 64);
        v += __shfl_xor(v, 32, 64);
        lpart[jb] = v;
    }
    if (lane < 16) {
#pragma unroll
        for (int jb = 0; jb < 8; ++jb)
            lred[w][jb * 16 + l15] = lpart[jb];
    }
    __syncthreads();
    if (tid < 128) {
        float s = lred[0][tid] + lred[1][tid] + lred[2][tid] + lred[3][tid];
        lbuf[((size_t)sp * 4 + b) * N_PIX + j0 + tid] = s;
    }

    // ---- A partial store (bf16, unnormalized)
    unsigned short* Ab = Abuf + ((size_t)sp * 4 + b) * 256 * N_PIX;
#pragma unroll
    for (int cb = 0; cb < 4; ++cb) {
        int c = w * 64 + cb * 16 + quad * 4;
#pragma unroll
        for (int jb = 0; jb < 8; ++jb) {
            int j = j0 + jb * 16 + l15;
#pragma unroll
            for (int r = 0; r < 4; ++r)
                Ab[(size_t)(c + r) * N_PIX + j] = f2bf(acc[cb][jb][r]);
        }
    }
}

// ---------------------------------------------------------------------------
// combine: out = x + g * (sum_s A_s) / (sum_s l_s);  A is bf16.
// ---------------------------------------------------------------------------
__global__ __launch_bounds__(256) void combine_kernel(
    const unsigned short* __restrict__ A, const float* __restrict__ L,
    const float* __restrict__ x, const float* __restrict__ gamma,
    float* __restrict__ out, int split)
{
    const size_t CH = (size_t)4 * 256 * N_PIX;
    size_t flat = ((size_t)blockIdx.x * 256 + threadIdx.x) * 8;
    int j = (int)(flat & (N_PIX - 1));
    int b = (int)(flat >> 20);

    float a[8] = {0.f, 0.f, 0.f, 0.f, 0.f, 0.f, 0.f, 0.f};
    float l[8] = {0.f, 0.f, 0.f, 0.f, 0.f, 0.f, 0.f, 0.f};
    for (int s = 0; s < split; ++s) {
        ushort4 av0 = *(const ushort4*)&A[flat + (size_t)s * CH];
        ushort4 av1 = *(const ushort4*)&A[flat + (size_t)s * CH + 4];
        a[0] += bf2f(av0.x); a[1] += bf2f(av0.y); a[2] += bf2f(av0.z); a[3] += bf2f(av0.w);
        a[4] += bf2f(av1.x); a[5] += bf2f(av1.y); a[6] += bf2f(av1.z); a[7] += bf2f(av1.w);
        float4 l0 = *(const float4*)&L[((size_t)s * 4 + b) * N_PIX + j];
        float4 l1 = *(const float4*)&L[((size_t)s * 4 + b) * N_PIX + j + 4];
        l[0] += l0.x; l[1] += l0.y; l[2] += l0.z; l[3] += l0.w;
        l[4] += l1.x; l[5] += l1.y; l[6] += l1.z; l[7] += l1.w;
    }
    float g = gamma[0];
    float4 x0 = *(const float4*)&x[flat];
    float4 x1 = *(const float4*)&x[flat + 4];
    float4 o0, o1;
    o0.x = x0.x + g * a[0] / l[0];
    o0.y = x0.y + g * a[1] / l[1];
    o0.z = x0.z + g * a[2] / l[2];
    o0.w = x0.w + g * a[3] / l[3];
    o1.x = x1.x + g * a[4] / l[4];
    o1.y = x1.y + g * a[5] / l[5];
    o1.z = x1.z + g * a[6] / l[6];
    o1.w = x1.w + g * a[7] / l[7];
    *(float4*)&out[flat]     = o0;
    *(float4*)&out[flat + 4] = o1;
}

// ---------------------------------------------------------------------------
extern "C" void kernel_launch(void* const* d_in, const int* in_sizes, int n_in,
                              void* d_out, int out_size, void* d_ws, size_t ws_size,
                              hipStream_t stream)
{
    const float* x     = (const float*)d_in[0];
    const float* wq    = (const float*)d_in[1];
    const float* bq    = (const float*)d_in[2];
    const float* wk    = (const float*)d_in[3];
    const float* bk    = (const float*)d_in[4];
    const float* wv    = (const float*)d_in[5];
    const float* bv    = (const float*)d_in[6];
    const float* gamma = (const float*)d_in[7];
    float* out = (float*)d_out;

    const size_t szQTel  = (size_t)4 * N_PIX * 32;        // elements (ushort)
    const size_t szVBFel = (size_t)4 * 256 * N_PIX;
    const size_t szXBFel = (size_t)4 * N_PIX * 256;
    const size_t szWel   = (size_t)72 * 320 * 32;
    const size_t fixedB  = (2 * szQTel + szVBFel + szXBFel + szWel) * 2;

    int split = 4;
    while (split > 1) {
        size_t need = fixedB
                    + (size_t)split * 4 * 256 * N_PIX * 2    // A bf16
                    + (size_t)split * 4 * N_PIX * 4;         // l fp32
        if (need <= ws_size) break;
        split >>= 1;
    }

    unsigned short* Abuf = (unsigned short*)d_ws;
    float* lbuf = (float*)(Abuf + (size_t)split * 4 * 256 * N_PIX);
    unsigned short* qt   = (unsigned short*)(lbuf + (size_t)split * 4 * N_PIX);
    unsigned short* kt   = qt + szQTel;
    unsigned short* vbf  = kt + szQTel;
    unsigned short* xbf  = vbf + szVBFel;
    unsigned short* wAll = xbf + szXBFel;

    x_transpose<<<dim3(N_PIX / 64, 4, 4), 256, 0, stream>>>(x, xbf);
    w_transform<<<dim3((72 * 320 * 4 + 255) / 256), 256, 0, stream>>>(wq, wk, wv, wAll);

    conv_gemm_all<<<dim3(N_PIX / 128, 5, 4), 256, 0, stream>>>(
        xbf, wAll, bq, bk, bv, vbf, qt, kt);

    fused_attn_mfma<<<dim3(N_PIX / 128, 4, split), 256, 0, stream>>>(
        qt, kt, vbf, Abuf, lbuf, N_PIX / split);

    combine_kernel<<<dim3((4 * 256 * N_PIX) / (256 * 8)), 256, 0, stream>>>(
        Abuf, lbuf, x, gamma, out, split);
}

// Round 9
// 188.232 us; speedup vs baseline: 1.2495x; 1.2495x over previous
//
#include <hip/hip_runtime.h>
#include <cstddef>

#define N_PIX 4096
#define HW 64
#define LOG2E 1.4426950408889634f
#define SHIFT2 28.8539008177793f   // 20 * log2(e)

typedef __attribute__((ext_vector_type(8))) short bf16x8;
typedef __attribute__((ext_vector_type(4))) float f32x4;

static __device__ __forceinline__ unsigned short f2bf(float f) {
    union { float f; unsigned u; } v; v.f = f;
    unsigned r = v.u + 0x7fffu + ((v.u >> 16) & 1u);   // RNE
    return (unsigned short)(r >> 16);
}
static __device__ __forceinline__ float bf2f(unsigned short s) {
    union { unsigned u; float f; } v; v.u = (unsigned)s << 16;
    return v.f;
}
// (bf16(hi)<<16)|bf16(lo), truncating: one v_perm_b32
static __device__ __forceinline__ unsigned pack_bf16_trunc(float lo, float hi) {
    union { float f; unsigned u; } a, b; a.f = hi; b.f = lo;
    return __builtin_amdgcn_perm(a.u, b.u, 0x07060302u);
}

// ---------------------------------------------------------------------------
// x [b][256 ci][4096 px] fp32  ->  xbf [b][4096 px][256 ci] bf16
// ---------------------------------------------------------------------------
__global__ __launch_bounds__(256) void x_transpose(
    const float* __restrict__ x, unsigned short* __restrict__ xbf)
{
    __shared__ unsigned short Ts[64][72];
    const int tid = threadIdx.x;
    const int px0 = blockIdx.x * 64, ci0 = blockIdx.y * 64, b = blockIdx.z;
    const float* xb = x + ((size_t)b * 256 + ci0) * N_PIX;

#pragma unroll
    for (int r = 0; r < 4; ++r) {
        int c = r * 16 + (tid >> 4);
        int p4 = (tid & 15) * 4;
        float4 v = *(const float4*)&xb[(size_t)c * N_PIX + px0 + p4];
        Ts[c][p4 + 0] = f2bf(v.x);
        Ts[c][p4 + 1] = f2bf(v.y);
        Ts[c][p4 + 2] = f2bf(v.z);
        Ts[c][p4 + 3] = f2bf(v.w);
    }
    __syncthreads();
#pragma unroll
    for (int r = 0; r < 2; ++r) {
        int id = tid * 2 + r;
        int p = id >> 3, c8 = (id & 7) * 8;
        ushort4 lo, hi;
        lo.x = Ts[c8 + 0][p]; lo.y = Ts[c8 + 1][p];
        lo.z = Ts[c8 + 2][p]; lo.w = Ts[c8 + 3][p];
        hi.x = Ts[c8 + 4][p]; hi.y = Ts[c8 + 5][p];
        hi.z = Ts[c8 + 6][p]; hi.w = Ts[c8 + 7][p];
        size_t off = ((size_t)b * N_PIX + px0 + p) * 256 + ci0 + c8;
        *(ushort4*)&xbf[off]     = lo;
        *(ushort4*)&xbf[off + 4] = hi;
    }
}

// ---------------------------------------------------------------------------
// Weights -> wAll [kb 0..71][320 rows][32 kin] bf16 (A-frag order).
// Rows: 0..255 wv, 256..287 wq (scaled by log2e), 288..319 wk.
// ---------------------------------------------------------------------------
__global__ __launch_bounds__(256) void w_transform(
    const float* __restrict__ wq, const float* __restrict__ wk,
    const float* __restrict__ wv, unsigned short* __restrict__ wAll)
{
    int gid = blockIdx.x * 256 + threadIdx.x;
    if (gid >= 72 * 320 * 4) return;
    int part = gid & 3;
    int m = (gid >> 2) % 320;
    int kb = gid / 1280;
    int t = kb >> 3;
    int ci0 = (kb & 7) * 32 + part * 8;
    const float* src; int co; float sc = 1.f;
    if (m < 256)      { src = wv; co = m; }
    else if (m < 288) { src = wq; co = m - 256; sc = LOG2E; }
    else              { src = wk; co = m - 288; }
    ushort4 lo, hi;
    lo.x = f2bf(sc * src[((size_t)co * 256 + ci0 + 0) * 9 + t]);
    lo.y = f2bf(sc * src[((size_t)co * 256 + ci0 + 1) * 9 + t]);
    lo.z = f2bf(sc * src[((size_t)co * 256 + ci0 + 2) * 9 + t]);
    lo.w = f2bf(sc * src[((size_t)co * 256 + ci0 + 3) * 9 + t]);
    hi.x = f2bf(sc * src[((size_t)co * 256 + ci0 + 4) * 9 + t]);
    hi.y = f2bf(sc * src[((size_t)co * 256 + ci0 + 5) * 9 + t]);
    hi.z = f2bf(sc * src[((size_t)co * 256 + ci0 + 6) * 9 + t]);
    hi.w = f2bf(sc * src[((size_t)co * 256 + ci0 + 7) * 9 + t]);
    size_t off = ((size_t)kb * 320 + m) * 32 + part * 8;
    *(ushort4*)&wAll[off]     = lo;
    *(ushort4*)&wAll[off + 4] = hi;
}

// ---------------------------------------------------------------------------
// Conv implicit GEMM v2: 128c x 128px tile (wave = 64x64), BK=32,
// ONE barrier/step.  A-frags: global, register double-buffered (prefetched
// a full step ahead; wAll is L2-hot).  B: LDS ping-pong, part index rotated
// by (row>>2)&3 so stores and reads are <=2-way (free).
// blockIdx.y = mt: 0,1 -> V rows mt*128..+128; 2 -> QK rows 256..319
// (QK: waves cover 32c x 64px, guard cb<2).
// ---------------------------------------------------------------------------
__global__ __launch_bounds__(256) void conv_gemm_v2(
    const unsigned short* __restrict__ xbf, const unsigned short* __restrict__ wAll,
    const float* __restrict__ bq, const float* __restrict__ bk,
    const float* __restrict__ bv,
    unsigned short* __restrict__ vbf, unsigned short* __restrict__ qt,
    unsigned short* __restrict__ kt)
{
    const int tid = threadIdx.x;
    const int w = tid >> 6, lane = tid & 63, quad = lane >> 4, l15 = lane & 15;
    const int px0 = blockIdx.x * 128;
    const int mt  = blockIdx.y;
    const int b   = blockIdx.z;
    const bool qk = (mt == 2);
    const int row0 = qk ? 256 : mt * 128;
    const int NCB  = qk ? 2 : 4;
    const int wc0  = (w & 1) * (qk ? 32 : 64);
    const int wp0  = (w >> 1) * 64;

    __shared__ unsigned short Bl[2][128 * 40];   // 20 KB ping-pong

    const unsigned short* xb = xbf + (size_t)b * N_PIX * 256;

    // B staging: lane -> row tid>>1, 32 B (2 parts) at bp0
    const int brow = tid >> 1;
    const int bp0  = (tid & 1) * 2;
    const int bswz = (brow >> 2) & 3;
    const int py = (px0 + brow) >> 6, pxc = brow & 63;

    f32x4 acc[4][4];
#pragma unroll
    for (int cb = 0; cb < 4; ++cb)
#pragma unroll
        for (int jb = 0; jb < 4; ++jb) acc[cb][jb] = (f32x4){0.f, 0.f, 0.f, 0.f};

    const unsigned short* aBase = wAll + ((size_t)(row0 + wc0 + l15) * 32 + quad * 8);

    auto load_a = [&](int kb, bf16x8* af) {
        const unsigned short* p = aBase + (size_t)kb * (320 * 32);
#pragma unroll
        for (int cb = 0; cb < 4; ++cb)
            if (cb < NCB) af[cb] = *(const bf16x8*)&p[cb * 512];
    };

    bf16x8 bS[2];
    auto load_b = [&](int kb) {
        int t = kb >> 3, ci0 = (kb & 7) << 5;
        int dy = t / 3 - 1, dx = t - (t / 3) * 3 - 1;
        int gy = py + dy, gx = pxc + dx;
        if ((unsigned)gy < 64u && (unsigned)gx < 64u) {
            const unsigned short* s = xb + ((size_t)(gy * 64 + gx) * 256 + ci0 + bp0 * 8);
            bS[0] = *(const bf16x8*)&s[0];
            bS[1] = *(const bf16x8*)&s[8];
        } else {
            bS[0] = (bf16x8){0,0,0,0,0,0,0,0};
            bS[1] = (bf16x8){0,0,0,0,0,0,0,0};
        }
    };
    auto store_b = [&](int buf) {
        int p0 = (bp0 + bswz) & 3;
        int p1 = (bp0 + 1 + bswz) & 3;
        *(bf16x8*)&Bl[buf][brow * 40 + p0 * 8] = bS[0];
        *(bf16x8*)&Bl[buf][brow * 40 + p1 * 8] = bS[1];
    };

    bf16x8 afC[4], afN[4];
    load_a(0, afC);
    load_b(0);
    store_b(0);

    for (int kb = 0; kb < 72; ++kb) {
        __syncthreads();                       // Bl[kb&1] visible
        const bool hasN = (kb + 1 < 72);
        if (hasN) { load_b(kb + 1); load_a(kb + 1, afN); }   // prefetch

        bf16x8 bf[4];
#pragma unroll
        for (int jb = 0; jb < 4; ++jb) {
            int row = wp0 + jb * 16 + l15;
            int pp = (quad + (row >> 2)) & 3;
            bf[jb] = *(const bf16x8*)&Bl[kb & 1][row * 40 + pp * 8];
        }
#pragma unroll
        for (int cb = 0; cb < 4; ++cb)
            if (cb < NCB)
#pragma unroll
                for (int jb = 0; jb < 4; ++jb)
                    acc[cb][jb] = __builtin_amdgcn_mfma_f32_16x16x32_bf16(
                        afC[cb], bf[jb], acc[cb][jb], 0, 0, 0);

        if (hasN) {
            store_b((kb + 1) & 1);             // other buffer: safe pre-barrier
#pragma unroll
            for (int cb = 0; cb < 4; ++cb) afC[cb] = afN[cb];
        }
    }

    if (!qk) {
#pragma unroll
        for (int cb = 0; cb < 4; ++cb) {
            int c = mt * 128 + wc0 + cb * 16 + quad * 4;
#pragma unroll
            for (int r = 0; r < 4; ++r) {
                float bias = bv[c + r];
#pragma unroll
                for (int jb = 0; jb < 4; ++jb) {
                    int px = px0 + wp0 + jb * 16 + l15;
                    vbf[((size_t)b * 256 + c + r) * N_PIX + px] = f2bf(acc[cb][jb][r] + bias);
                }
            }
        }
    } else {
#pragma unroll
        for (int cb = 0; cb < 2; ++cb) {
            int cl = wc0 + cb * 16 + quad * 4;
#pragma unroll
            for (int r = 0; r < 4; ++r) {
                int c = cl + r;
                float bias = (c < 32) ? bq[c] * LOG2E : bk[c - 32];
#pragma unroll
                for (int jb = 0; jb < 4; ++jb) {
                    int px = px0 + wp0 + jb * 16 + l15;
                    unsigned short val = f2bf(acc[cb][jb][r] + bias);
                    if (c < 32)
                        qt[((size_t)b * N_PIX + px) * 32 + c] = val;
                    else
                        kt[((size_t)b * N_PIX + px) * 32 + (c - 32)] = val;
                }
            }
        }
    }
}

// ---------------------------------------------------------------------------
// MFMA flash attention — j-tile 128, single barrier/iter, Pfrag ping-pong.
// qt pre-scaled by log2e; shift folded into MFMA C-init; P packed with
// v_perm_b32 (truncating bf16).
// ---------------------------------------------------------------------------
__global__ __launch_bounds__(256, 2) void fused_attn_mfma(
    const unsigned short* __restrict__ qt, const unsigned short* __restrict__ kt,
    const unsigned short* __restrict__ vbf,
    unsigned short* __restrict__ Abuf, float* __restrict__ lbuf, int iRange)
{
    const int tid  = threadIdx.x;
    const int w    = tid >> 6;
    const int lane = tid & 63;
    const int quad = lane >> 4;
    const int l15  = lane & 15;
    const int j0   = blockIdx.x * 128;
    const int b    = blockIdx.y;
    const int sp   = blockIdx.z;
    const int iBeg = sp * iRange;
    const int NI   = iRange / 64;

    const unsigned short* qtb = qt + (size_t)b * N_PIX * 32;
    const unsigned short* ktb = kt + (size_t)b * N_PIX * 32;
    const unsigned short* vb  = vbf + (size_t)b * 256 * N_PIX;

    __shared__ unsigned Pfrag[2][4096];   // 32 KB ping-pong (dwords)
    __shared__ float lred[4][128];

    bf16x8 kf[8];
#pragma unroll
    for (int jb = 0; jb < 8; ++jb)
        kf[jb] = *(const bf16x8*)&ktb[((size_t)(j0 + jb * 16 + l15)) * 32 + quad * 8];

    f32x4 acc[4][8];
#pragma unroll
    for (int cb = 0; cb < 4; ++cb)
#pragma unroll
        for (int jb = 0; jb < 8; ++jb)
            acc[cb][jb] = (f32x4){0.f, 0.f, 0.f, 0.f};

    float lpart[8] = {0.f, 0.f, 0.f, 0.f, 0.f, 0.f, 0.f, 0.f};

    const int wFrag = w >> 1;
    const int wL    = ((w & 1) << 5) + ((quad >> 1) << 4) + l15;
    const int wEl2  = (quad & 1) << 1;   // dword offset 0 or 2

    bf16x8 va[2][4];

    auto s_phase = [&](bf16x8 qa, int buf) {
#pragma unroll
        for (int jb = 0; jb < 8; ++jb) {
            f32x4 s = __builtin_amdgcn_mfma_f32_16x16x32_bf16(
                qa, kf[jb], (f32x4){-SHIFT2, -SHIFT2, -SHIFT2, -SHIFT2}, 0, 0, 0);
            float p0 = __builtin_amdgcn_exp2f(s[0]);
            float p1 = __builtin_amdgcn_exp2f(s[1]);
            float p2 = __builtin_amdgcn_exp2f(s[2]);
            float p3 = __builtin_amdgcn_exp2f(s[3]);
            lpart[jb] += (p0 + p1) + (p2 + p3);
            unsigned u0 = pack_bf16_trunc(p0, p1);
            unsigned u1 = pack_bf16_trunc(p2, p3);
            unsigned base = (((jb << 1) + wFrag) * 64 + wL) * 4 + wEl2;
            Pfrag[buf][base]     = u0;
            Pfrag[buf][base + 1] = u1;
        }
    };

    auto load_qa = [&](int i0) {
        return *(const bf16x8*)&qtb[((size_t)(i0 + w * 16 + l15)) * 32 + quad * 8];
    };
    auto load_va = [&](int i0) {
#pragma unroll
        for (int ks = 0; ks < 2; ++ks)
#pragma unroll
            for (int cb = 0; cb < 4; ++cb)
                va[ks][cb] = *(const bf16x8*)&vb[((size_t)(w * 64 + cb * 16 + l15)) * N_PIX
                                                 + i0 + ks * 32 + quad * 8];
    };

    // prologue
    load_va(iBeg);
    s_phase(load_qa(iBeg), 0);

    for (int n = 0; n < NI; ++n) {
        __syncthreads();               // P[n&1] ready for all waves
        const bool hasN = (n + 1 < NI);
        const int inext = iBeg + (n + 1) * 64;
        bf16x8 qaN;
        if (hasN) qaN = load_qa(inext);

        // ---- O(n): reads Pfrag[n&1] + va (loaded for iter n)
#pragma unroll
        for (int ks = 0; ks < 2; ++ks) {
            bf16x8 pb[8];
#pragma unroll
            for (int jb = 0; jb < 8; ++jb)
                pb[jb] = *(const bf16x8*)&Pfrag[n & 1][(((jb << 1) + ks) * 64 + lane) * 4];
#pragma unroll
            for (int cb = 0; cb < 4; ++cb)
#pragma unroll
                for (int jb = 0; jb < 8; ++jb)
                    acc[cb][jb] = __builtin_amdgcn_mfma_f32_16x16x32_bf16(
                        va[ks][cb], pb[jb], acc[cb][jb], 0, 0, 0);
        }

        // ---- prefetch va(n+1) then S(n+1) into other buffer
        if (hasN) {
            load_va(inext);
            s_phase(qaN, (n + 1) & 1);
        }
    }

    // ---- l reduction
#pragma unroll
    for (int jb = 0; jb < 8; ++jb) {
        float v = lpart[jb];
        v += __shfl_xor(v, 16, 64);
        v += __shfl_xor(v, 32, 64);
        lpart[jb] = v;
    }
    if (lane < 16) {
#pragma unroll
        for (int jb = 0; jb < 8; ++jb)
            lred[w][jb * 16 + l15] = lpart[jb];
    }
    __syncthreads();
    if (tid < 128) {
        float s = lred[0][tid] + lred[1][tid] + lred[2][tid] + lred[3][tid];
        lbuf[((size_t)sp * 4 + b) * N_PIX + j0 + tid] = s;
    }

    // ---- A partial store (bf16, unnormalized)
    unsigned short* Ab = Abuf + ((size_t)sp * 4 + b) * 256 * N_PIX;
#pragma unroll
    for (int cb = 0; cb < 4; ++cb) {
        int c = w * 64 + cb * 16 + quad * 4;
#pragma unroll
        for (int jb = 0; jb < 8; ++jb) {
            int j = j0 + jb * 16 + l15;
#pragma unroll
            for (int r = 0; r < 4; ++r)
                Ab[(size_t)(c + r) * N_PIX + j] = f2bf(acc[cb][jb][r]);
        }
    }
}

// ---------------------------------------------------------------------------
// combine: out = x + g * (sum_s A_s) / (sum_s l_s);  A is bf16.
// ---------------------------------------------------------------------------
__global__ __launch_bounds__(256) void combine_kernel(
    const unsigned short* __restrict__ A, const float* __restrict__ L,
    const float* __restrict__ x, const float* __restrict__ gamma,
    float* __restrict__ out, int split)
{
    const size_t CH = (size_t)4 * 256 * N_PIX;
    size_t flat = ((size_t)blockIdx.x * 256 + threadIdx.x) * 8;
    int j = (int)(flat & (N_PIX - 1));
    int b = (int)(flat >> 20);

    float a[8] = {0.f, 0.f, 0.f, 0.f, 0.f, 0.f, 0.f, 0.f};
    float l[8] = {0.f, 0.f, 0.f, 0.f, 0.f, 0.f, 0.f, 0.f};
    for (int s = 0; s < split; ++s) {
        ushort4 av0 = *(const ushort4*)&A[flat + (size_t)s * CH];
        ushort4 av1 = *(const ushort4*)&A[flat + (size_t)s * CH + 4];
        a[0] += bf2f(av0.x); a[1] += bf2f(av0.y); a[2] += bf2f(av0.z); a[3] += bf2f(av0.w);
        a[4] += bf2f(av1.x); a[5] += bf2f(av1.y); a[6] += bf2f(av1.z); a[7] += bf2f(av1.w);
        float4 l0 = *(const float4*)&L[((size_t)s * 4 + b) * N_PIX + j];
        float4 l1 = *(const float4*)&L[((size_t)s * 4 + b) * N_PIX + j + 4];
        l[0] += l0.x; l[1] += l0.y; l[2] += l0.z; l[3] += l0.w;
        l[4] += l1.x; l[5] += l1.y; l[6] += l1.z; l[7] += l1.w;
    }
    float g = gamma[0];
    float4 x0 = *(const float4*)&x[flat];
    float4 x1 = *(const float4*)&x[flat + 4];
    float4 o0, o1;
    o0.x = x0.x + g * a[0] / l[0];
    o0.y = x0.y + g * a[1] / l[1];
    o0.z = x0.z + g * a[2] / l[2];
    o0.w = x0.w + g * a[3] / l[3];
    o1.x = x1.x + g * a[4] / l[4];
    o1.y = x1.y + g * a[5] / l[5];
    o1.z = x1.z + g * a[6] / l[6];
    o1.w = x1.w + g * a[7] / l[7];
    *(float4*)&out[flat]     = o0;
    *(float4*)&out[flat + 4] = o1;
}

// ---------------------------------------------------------------------------
extern "C" void kernel_launch(void* const* d_in, const int* in_sizes, int n_in,
                              void* d_out, int out_size, void* d_ws, size_t ws_size,
                              hipStream_t stream)
{
    const float* x     = (const float*)d_in[0];
    const float* wq    = (const float*)d_in[1];
    const float* bq    = (const float*)d_in[2];
    const float* wk    = (const float*)d_in[3];
    const float* bk    = (const float*)d_in[4];
    const float* wv    = (const float*)d_in[5];
    const float* bv    = (const float*)d_in[6];
    const float* gamma = (const float*)d_in[7];
    float* out = (float*)d_out;

    const size_t szQTel  = (size_t)4 * N_PIX * 32;        // elements (ushort)
    const size_t szVBFel = (size_t)4 * 256 * N_PIX;
    const size_t szXBFel = (size_t)4 * N_PIX * 256;
    const size_t szWel   = (size_t)72 * 320 * 32;
    const size_t fixedB  = (2 * szQTel + szVBFel + szXBFel + szWel) * 2;

    int split = 4;
    while (split > 1) {
        size_t need = fixedB
                    + (size_t)split * 4 * 256 * N_PIX * 2    // A bf16
                    + (size_t)split * 4 * N_PIX * 4;         // l fp32
        if (need <= ws_size) break;
        split >>= 1;
    }

    unsigned short* Abuf = (unsigned short*)d_ws;
    float* lbuf = (float*)(Abuf + (size_t)split * 4 * 256 * N_PIX);
    unsigned short* qt   = (unsigned short*)(lbuf + (size_t)split * 4 * N_PIX);
    unsigned short* kt   = qt + szQTel;
    unsigned short* vbf  = kt + szQTel;
    unsigned short* xbf  = vbf + szVBFel;
    unsigned short* wAll = xbf + szXBFel;

    x_transpose<<<dim3(N_PIX / 64, 4, 4), 256, 0, stream>>>(x, xbf);
    w_transform<<<dim3((72 * 320 * 4 + 255) / 256), 256, 0, stream>>>(wq, wk, wv, wAll);

    conv_gemm_v2<<<dim3(N_PIX / 128, 3, 4), 256, 0, stream>>>(
        xbf, wAll, bq, bk, bv, vbf, qt, kt);

    fused_attn_mfma<<<dim3(N_PIX / 128, 4, split), 256, 0, stream>>>(
        qt, kt, vbf, Abuf, lbuf, N_PIX / split);

    combine_kernel<<<dim3((4 * 256 * N_PIX) / (256 * 8)), 256, 0, stream>>>(
        Abuf, lbuf, x, gamma, out, split);
}